// Round 11
// baseline (288.803 us; speedup 1.0000x reference)
//
#include <hip/hip_runtime.h>
#include <hip/hip_cooperative_groups.h>
#include <stdint.h>

#define ET 128
#define ES 16
#define NF 34   // partial fields: 0=sum_w 1=sum_kl 2..17=t_counts 18..33=s_counts

namespace cg = cooperative_groups;

__host__ __device__ inline uint32_t rotl32(uint32_t x, int r) {
#ifdef __HIP_DEVICE_COMPILE__
  return __builtin_amdgcn_alignbit(x, x, (uint32_t)(32 - r));  // 1 instr
#else
  return (x << r) | (x >> (32 - r));
#endif
}

__host__ __device__ inline void tf2x32(uint32_t k0, uint32_t k1,
                                       uint32_t& x0, uint32_t& x1) {
  uint32_t ks2 = k0 ^ k1 ^ 0x1BD11BDAu;
  x0 += k0; x1 += k1;
#define TF_ROT(r) { x0 += x1; x1 = rotl32(x1, r); x1 ^= x0; }
  TF_ROT(13) TF_ROT(15) TF_ROT(26) TF_ROT(6)
  x0 += k1;  x1 += ks2 + 1u;
  TF_ROT(17) TF_ROT(29) TF_ROT(16) TF_ROT(24)
  x0 += ks2; x1 += k0 + 2u;
  TF_ROT(13) TF_ROT(15) TF_ROT(26) TF_ROT(6)
  x0 += k0;  x1 += k1 + 3u;
  TF_ROT(17) TF_ROT(29) TF_ROT(16) TF_ROT(24)
  x0 += k1;  x1 += ks2 + 4u;
  TF_ROT(13) TF_ROT(15) TF_ROT(26) TF_ROT(6)
  x0 += ks2; x1 += k0 + 5u;
#undef TF_ROT
}

// partitionable threefry uniform for flat index j; u = f-1 in [0,1).
// (JAX's TINY add/clamp is identity for u>0; u==0 -> e=+inf, never wins.)
__device__ inline float unif01m(uint32_t s0, uint32_t s1, uint32_t j) {
  uint32_t x0 = 0u, x1 = j;
  tf2x32(s0, s1, x0, x1);
  uint32_t bits = x0 ^ x1;
  return __uint_as_float((bits >> 9) | 0x3F800000u) - 1.0f;
}

__device__ inline float fastrcp(float x) { return __builtin_amdgcn_rcpf(x); }

template <int CTRL>
__device__ inline uint32_t dpp32(uint32_t v) {
  return (uint32_t)__builtin_amdgcn_update_dpp((int)v, (int)v, CTRL, 0xF, 0xF,
                                               false);
}

// Reduce 34 x G per-block partials (field-major) and compute the final loss.
// Runs on one 256-thread block; agent-scope loads for cross-XCD visibility.
__device__ inline void reduce_and_finalize(const double* __restrict__ acc,
                                           int G, float* __restrict__ out) {
  __shared__ double tot[NF];
  const int tid = threadIdx.x;
  const int c = tid & 7;
  const int CH = (G + 7) >> 3;
  for (int f = tid >> 3; f < NF; f += 32) {
    double s = 0.0;
    const int j0 = c * CH;
    const int j1 = (j0 + CH < G) ? j0 + CH : G;
    const double* src = acc + (size_t)f * G;
    for (int j = j0; j < j1; ++j)
      s += __hip_atomic_load(&src[j], __ATOMIC_RELAXED,
                             __HIP_MEMORY_SCOPE_AGENT);
    s += __shfl_xor(s, 1); s += __shfl_xor(s, 2); s += __shfl_xor(s, 4);
    if (c == 0) tot[f] = s;
  }
  __syncthreads();
  if (tid >= 64) return;

  const double EPSD = 1e-8;
  double tv = (tid < ES) ? tot[2 + tid] : 0.0;
  double sv = (tid < ES) ? tot[2 + ES + tid] : 0.0;
  double tsum = tv, ssum = sv;
#pragma unroll
  for (int off = 8; off; off >>= 1) {
    tsum += __shfl_xor(tsum, off);
    ssum += __shfl_xor(ssum, off);
  }
  double ta = tv / tsum + EPSD;
  double sa = sv / ssum + EPSD;
  double ta2 = (tid < ES) ? ta : 0.0;
  double sa2 = (tid < ES) ? sa : 0.0;
#pragma unroll
  for (int off = 8; off; off >>= 1) {
    ta2 += __shfl_xor(ta2, off);
    sa2 += __shfl_xor(sa2, off);
  }
  ta2 += (double)(ET - ES) * EPSD;   // 112 zero bins contribute EPS each
  sa2 += (double)(ET - ES) * EPSD;
  double tn = ta / ta2, sn = sa / sa2;
  double ci = (tid < ES) ? tn * (log(tn) - log(sn)) : 0.0;
#pragma unroll
  for (int off = 8; off; off >>= 1) ci += __shfl_xor(ci, off);

  if (tid == 0) {
    double ta0 = EPSD / ta2, sa0 = EPSD / sa2;
    double cov = ci + (double)(ET - ES) * ta0 * (log(ta0) - log(sa0));
    cov /= (double)ET;
    double feat = tot[1] / fmax(tot[0], EPSD);
    out[0] = (float)(feat + 0.5 * cov);
  }
}

// 16 lanes/token, 8 experts/lane, 4 tokens/wave.
// Winner = argmin_e( -log(u_e)/p_e ); u32 key with idx in low 7 mantissa bits.
// COOP=1: grid.sync + fused finalize. COOP=0: partials only.
template <int COOP>
__launch_bounds__(256, 8)
__global__ void sample_kernel(const float* __restrict__ tg,
                              const float* __restrict__ sg,
                              const int* __restrict__ am,
                              double* __restrict__ acc,
                              float* __restrict__ out,
                              uint32_t s00, uint32_t s01,
                              uint32_t s10, uint32_t s11,
                              uint32_t s20, uint32_t s21,
                              int N, int total_waves) {
  __shared__ float lds_t[ES], lds_s[ES];
  __shared__ float lds_w[4], lds_kl[4];
  if (threadIdx.x < ES) { lds_t[threadIdx.x] = 0.f; lds_s[threadIdx.x] = 0.f; }
  __syncthreads();

  const int wslot = threadIdx.x >> 6;
  const int wid = blockIdx.x * 4 + wslot;
  const int lane = threadIdx.x & 63;
  const int gl = lane & 15;
  const int gbase = lane & 0x30;
  const int stride = total_waves * 4;
  const float NLN2 = -0.69314718055994530942f;

  float sum_w = 0.f, sum_kl = 0.f;

#define STEP(KA, KB, LAST)                                                   \
  {                                                                          \
    float e[8];                                                              \
    _Pragma("unroll")                                                        \
    for (int q = 0; q < 8; ++q)                                              \
      e[q] = __log2f(unif01m(KA, KB, jb + (uint32_t)q)) * invn[q];           \
    uint32_t key = 0xFFFFFFFFu;                                              \
    _Pragma("unroll")                                                        \
    for (int q = 0; q < 8; ++q) {                                            \
      uint32_t kq = (__float_as_uint(e[q]) & 0xFFFFFF80u)                    \
                    | (uint32_t)(ebase + q);                                 \
      key = (kq < key) ? kq : key;                                           \
    }                                                                        \
    { uint32_t o;                                                            \
      o = dpp32<0x128>(key); key = (o < key) ? o : key;                      \
      o = dpp32<0x124>(key); key = (o < key) ? o : key;                      \
      o = dpp32<0x122>(key); key = (o < key) ? o : key;                      \
      o = dpp32<0x121>(key); key = (o < key) ? o : key;                      \
    }                                                                        \
    const int bi = (int)(key & 0x7Fu);                                       \
    const int wl = bi >> 3, wslt = bi & 7;                                   \
    float pw = p[0];                                                         \
    _Pragma("unroll")                                                        \
    for (int q = 1; q < 8; ++q) pw = (wslt == q) ? p[q] : pw;                \
    float w_abs = __shfl(pw, gbase | wl);                                    \
    float sgkl = __shfl(sgv, gbase | wl);                                    \
    float sgcv = __shfl(sgv, gbase | (bi & 15));                             \
    float wsv = w_abs * fastrcp(t) * vm;                                     \
    const bool lead = (gl == 0);                                             \
    sum_w += lead ? wsv : 0.f;                                               \
    float klt = (wslt == 0) ? (-__logf(sgkl)) * wsv : 0.f;                   \
    sum_kl += lead ? klt : 0.f;                                              \
    if (lead && bi < ES) {                                                   \
      atomicAdd(&lds_t[bi], wsv);                                            \
      atomicAdd(&lds_s[bi], sgcv * vm);                                      \
    }                                                                        \
    if (!(LAST)) {                                                           \
      const bool mt = (gl == wl);                                            \
      _Pragma("unroll")                                                      \
      for (int q = 0; q < 8; ++q) {                                          \
        bool hit = mt && (wslt == q);                                        \
        p[q] = hit ? p[q] * 0.5f : p[q];                                     \
        invn[q] = hit ? invn[q] * 2.0f : invn[q];                            \
      }                                                                      \
      t -= 0.5f * w_abs;                                                     \
    }                                                                        \
  }

  for (int base = wid * 4; base < N; base += stride) {
    const int nr = base + (lane >> 4);
    const int ok = (nr < N);
    const int n = ok ? nr : (N - 1);

    const float4* r4 = (const float4*)(tg + (size_t)n * ET + gl * 8);
    float4 aa = r4[0], bb = r4[1];
    float p[8] = {aa.x, aa.y, aa.z, aa.w, bb.x, bb.y, bb.z, bb.w};
    float sgv = sg[(size_t)n * ES + gl];
    float vm = ok ? (float)am[n] : 0.f;

    float invn[8];
#pragma unroll
    for (int q = 0; q < 8; ++q) invn[q] = NLN2 * fastrcp(p[q]);

    float t = 1.0f;
    const uint32_t jb = (uint32_t)n * ET + (uint32_t)(gl * 8);
    const int ebase = gl * 8;
    STEP(s00, s01, 0)
    STEP(s10, s11, 0)
    STEP(s20, s21, 1)
  }
#undef STEP

#pragma unroll
  for (int off = 32; off; off >>= 1) {
    sum_w += __shfl_xor(sum_w, off);
    sum_kl += __shfl_xor(sum_kl, off);
  }
  if (lane == 0) { lds_w[wslot] = sum_w; lds_kl[wslot] = sum_kl; }
  __syncthreads();

  // store-based per-block partials (overwrite -> no zero-init needed)
  const int G = gridDim.x;
  const int b = blockIdx.x;
  if (threadIdx.x == 0) {
    __hip_atomic_store(&acc[0 * (size_t)G + b],
                       (double)(lds_w[0] + lds_w[1] + lds_w[2] + lds_w[3]),
                       __ATOMIC_RELAXED, __HIP_MEMORY_SCOPE_AGENT);
    __hip_atomic_store(&acc[1 * (size_t)G + b],
                       (double)(lds_kl[0] + lds_kl[1] + lds_kl[2] + lds_kl[3]),
                       __ATOMIC_RELAXED, __HIP_MEMORY_SCOPE_AGENT);
  }
  if (threadIdx.x < ES) {
    __hip_atomic_store(&acc[(size_t)(2 + threadIdx.x) * G + b],
                       (double)lds_t[threadIdx.x],
                       __ATOMIC_RELAXED, __HIP_MEMORY_SCOPE_AGENT);
    __hip_atomic_store(&acc[(size_t)(2 + ES + threadIdx.x) * G + b],
                       (double)lds_s[threadIdx.x],
                       __ATOMIC_RELAXED, __HIP_MEMORY_SCOPE_AGENT);
  }

  if constexpr (COOP) {
    cg::this_grid().sync();
    if (blockIdx.x != 0) return;
    reduce_and_finalize(acc, G, out);
  }
}

__launch_bounds__(256)
__global__ void finalize_kernel(const double* __restrict__ acc, int G,
                                float* __restrict__ out) {
  reduce_and_finalize(acc, G, out);
}

extern "C" void kernel_launch(void* const* d_in, const int* in_sizes, int n_in,
                              void* d_out, int out_size, void* d_ws, size_t ws_size,
                              hipStream_t stream) {
  const float* tg = (const float*)d_in[0];
  const float* sg = (const float*)d_in[1];
  const int*   am = (const int*)d_in[4];
  int N = in_sizes[4];  // B*S tokens

  // key chain: key = jax.random.key(42); per step foldlike split (partitionable)
  uint32_t key0 = 0u, key1 = 42u;
  uint32_t subs[3][2];
  for (int k = 0; k < 3; ++k) {
    uint32_t a0 = 0u, a1 = 0u; tf2x32(key0, key1, a0, a1);  // new key
    uint32_t b0 = 0u, b1 = 1u; tf2x32(key0, key1, b0, b1);  // subkey
    subs[k][0] = b0; subs[k][1] = b1;
    key0 = a0; key1 = a1;
  }

  double* acc = (double*)d_ws;

  int blocks = (N + 15) / 16;
  if (blocks > 2048) blocks = 2048;
  if (blocks < 1) blocks = 1;
  int total_waves = blocks * 4;
  float* out = (float*)d_out;

  void* params[] = {
      (void*)&tg, (void*)&sg, (void*)&am, (void*)&acc, (void*)&out,
      (void*)&subs[0][0], (void*)&subs[0][1],
      (void*)&subs[1][0], (void*)&subs[1][1],
      (void*)&subs[2][0], (void*)&subs[2][1],
      (void*)&N, (void*)&total_waves};

  hipError_t err = hipLaunchCooperativeKernel(
      (const void*)sample_kernel<1>, dim3(blocks), dim3(256), params, 0,
      stream);
  if (err != hipSuccess) {
    (void)hipGetLastError();  // clear; memset-free two-kernel fallback
    sample_kernel<0><<<blocks, 256, 0, stream>>>(
        tg, sg, am, acc, out,
        subs[0][0], subs[0][1], subs[1][0], subs[1][1], subs[2][0], subs[2][1],
        N, total_waves);
    finalize_kernel<<<1, 256, 0, stream>>>(acc, blocks, out);
  }
}

// Round 12
// 109.201 us; speedup vs baseline: 2.6447x; 2.6447x over previous
//
#include <hip/hip_runtime.h>
#include <stdint.h>

#define ET 128
#define ES 16
#define NF 34   // partial fields: 0=sum_w 1=sum_kl 2..17=t_counts 18..33=s_counts

__host__ __device__ inline uint32_t rotl32(uint32_t x, int r) {
#ifdef __HIP_DEVICE_COMPILE__
  return __builtin_amdgcn_alignbit(x, x, (uint32_t)(32 - r));  // 1 instr
#else
  return (x << r) | (x >> (32 - r));
#endif
}

__host__ __device__ inline void tf2x32(uint32_t k0, uint32_t k1,
                                       uint32_t& x0, uint32_t& x1) {
  uint32_t ks2 = k0 ^ k1 ^ 0x1BD11BDAu;
  x0 += k0; x1 += k1;
#define TF_ROT(r) { x0 += x1; x1 = rotl32(x1, r); x1 ^= x0; }
  TF_ROT(13) TF_ROT(15) TF_ROT(26) TF_ROT(6)
  x0 += k1;  x1 += ks2 + 1u;
  TF_ROT(17) TF_ROT(29) TF_ROT(16) TF_ROT(24)
  x0 += ks2; x1 += k0 + 2u;
  TF_ROT(13) TF_ROT(15) TF_ROT(26) TF_ROT(6)
  x0 += k0;  x1 += k1 + 3u;
  TF_ROT(17) TF_ROT(29) TF_ROT(16) TF_ROT(24)
  x0 += k1;  x1 += ks2 + 4u;
  TF_ROT(13) TF_ROT(15) TF_ROT(26) TF_ROT(6)
  x0 += ks2; x1 += k0 + 5u;
#undef TF_ROT
}

// partitionable threefry uniform for flat index j; u = f-1 in [0,1).
// (JAX's TINY add/clamp is identity for u>0; u==0 -> e=+inf, never wins.)
__device__ inline float unif01m(uint32_t s0, uint32_t s1, uint32_t j) {
  uint32_t x0 = 0u, x1 = j;
  tf2x32(s0, s1, x0, x1);
  uint32_t bits = x0 ^ x1;
  return __uint_as_float((bits >> 9) | 0x3F800000u) - 1.0f;
}

__device__ inline float fastrcp(float x) { return __builtin_amdgcn_rcpf(x); }

template <int CTRL>
__device__ inline uint32_t dpp32(uint32_t v) {
  return (uint32_t)__builtin_amdgcn_update_dpp((int)v, (int)v, CTRL, 0xF, 0xF,
                                               false);
}

// 16 lanes/token, 8 experts/lane, 4 tokens/wave.
// Winner = argmin_e( -log(u_e)/p_e ) (exponential race == gumbel argmax).
// u32 score key with expert idx packed in the low 7 mantissa bits.
// NOTE: no min-waves launch-bounds arg — forcing 8 waves/EU capped VGPR at 32
// and spilled everything (R11: VALUBusy 90%->8%, 10x regression).
__launch_bounds__(256)
__global__ void sample_kernel(const float* __restrict__ tg,
                              const float* __restrict__ sg,
                              const int* __restrict__ am,
                              double* __restrict__ acc,
                              uint32_t s00, uint32_t s01,
                              uint32_t s10, uint32_t s11,
                              uint32_t s20, uint32_t s21,
                              int N, int total_waves) {
  __shared__ float lds_t[ES], lds_s[ES];
  __shared__ float lds_w[4], lds_kl[4];
  if (threadIdx.x < ES) { lds_t[threadIdx.x] = 0.f; lds_s[threadIdx.x] = 0.f; }
  __syncthreads();

  const int wslot = threadIdx.x >> 6;
  const int wid = blockIdx.x * 4 + wslot;
  const int lane = threadIdx.x & 63;
  const int gl = lane & 15;
  const int gbase = lane & 0x30;
  const int stride = total_waves * 4;
  const float NLN2 = -0.69314718055994530942f;

  float sum_w = 0.f, sum_kl = 0.f;

#define STEP(KA, KB, LAST)                                                   \
  {                                                                          \
    float e[8];                                                              \
    _Pragma("unroll")                                                        \
    for (int q = 0; q < 8; ++q)                                              \
      e[q] = __log2f(unif01m(KA, KB, jb + (uint32_t)q)) * invn[q];           \
    uint32_t key = 0xFFFFFFFFu;                                              \
    _Pragma("unroll")                                                        \
    for (int q = 0; q < 8; ++q) {                                            \
      uint32_t kq = (__float_as_uint(e[q]) & 0xFFFFFF80u)                    \
                    | (uint32_t)(ebase + q);                                 \
      key = (kq < key) ? kq : key;                                           \
    }                                                                        \
    { uint32_t o;                                                            \
      o = dpp32<0x128>(key); key = (o < key) ? o : key;                      \
      o = dpp32<0x124>(key); key = (o < key) ? o : key;                      \
      o = dpp32<0x122>(key); key = (o < key) ? o : key;                      \
      o = dpp32<0x121>(key); key = (o < key) ? o : key;                      \
    }                                                                        \
    const int bi = (int)(key & 0x7Fu);                                       \
    const int wl = bi >> 3, wslt = bi & 7;                                   \
    float pw = p[0];                                                         \
    _Pragma("unroll")                                                        \
    for (int q = 1; q < 8; ++q) pw = (wslt == q) ? p[q] : pw;                \
    float w_abs = __shfl(pw, gbase | wl);                                    \
    float sgkl = __shfl(sgv, gbase | wl);                                    \
    float sgcv = __shfl(sgv, gbase | (bi & 15));                             \
    float wsv = w_abs * fastrcp(t) * vm;                                     \
    const bool lead = (gl == 0);                                             \
    sum_w += lead ? wsv : 0.f;                                               \
    float klt = (wslt == 0) ? (-__logf(sgkl)) * wsv : 0.f;                   \
    sum_kl += lead ? klt : 0.f;                                              \
    if (lead && bi < ES) {                                                   \
      atomicAdd(&lds_t[bi], wsv);                                            \
      atomicAdd(&lds_s[bi], sgcv * vm);                                      \
    }                                                                        \
    if (!(LAST)) {                                                           \
      const bool mt = (gl == wl);                                            \
      _Pragma("unroll")                                                      \
      for (int q = 0; q < 8; ++q) {                                          \
        bool hit = mt && (wslt == q);                                        \
        p[q] = hit ? p[q] * 0.5f : p[q];                                     \
        invn[q] = hit ? invn[q] * 2.0f : invn[q];                            \
      }                                                                      \
      t -= 0.5f * w_abs;                                                     \
    }                                                                        \
  }

  for (int base = wid * 4; base < N; base += stride) {
    const int nr = base + (lane >> 4);
    const int ok = (nr < N);
    const int n = ok ? nr : (N - 1);

    const float4* r4 = (const float4*)(tg + (size_t)n * ET + gl * 8);
    float4 aa = r4[0], bb = r4[1];
    float p[8] = {aa.x, aa.y, aa.z, aa.w, bb.x, bb.y, bb.z, bb.w};
    float sgv = sg[(size_t)n * ES + gl];
    float vm = ok ? (float)am[n] : 0.f;

    float invn[8];
#pragma unroll
    for (int q = 0; q < 8; ++q) invn[q] = NLN2 * fastrcp(p[q]);

    float t = 1.0f;
    const uint32_t jb = (uint32_t)n * ET + (uint32_t)(gl * 8);
    const int ebase = gl * 8;
    STEP(s00, s01, 0)
    STEP(s10, s11, 0)
    STEP(s20, s21, 1)
  }
#undef STEP

#pragma unroll
  for (int off = 32; off; off >>= 1) {
    sum_w += __shfl_xor(sum_w, off);
    sum_kl += __shfl_xor(sum_kl, off);
  }
  if (lane == 0) { lds_w[wslot] = sum_w; lds_kl[wslot] = sum_kl; }
  __syncthreads();

  // store-based per-block partials (overwrite -> no zero-init, no memset node)
  const int G = gridDim.x;
  const int b = blockIdx.x;
  if (threadIdx.x == 0) {
    acc[0 * (size_t)G + b] =
        (double)(lds_w[0] + lds_w[1] + lds_w[2] + lds_w[3]);
    acc[1 * (size_t)G + b] =
        (double)(lds_kl[0] + lds_kl[1] + lds_kl[2] + lds_kl[3]);
  }
  if (threadIdx.x < ES) {
    acc[(size_t)(2 + threadIdx.x) * G + b] = (double)lds_t[threadIdx.x];
    acc[(size_t)(2 + ES + threadIdx.x) * G + b] = (double)lds_s[threadIdx.x];
  }
}

// Reduce 34 x G per-block partials (field-major) and compute the final loss.
__launch_bounds__(256)
__global__ void finalize_kernel(const double* __restrict__ acc, int G,
                                float* __restrict__ out) {
  __shared__ double tot[NF];
  const int tid = threadIdx.x;
  const int c = tid & 7;
  const int CH = (G + 7) >> 3;
  for (int f = tid >> 3; f < NF; f += 32) {
    double s = 0.0;
    const int j0 = c * CH;
    const int j1 = (j0 + CH < G) ? j0 + CH : G;
    const double* src = acc + (size_t)f * G;
    for (int j = j0; j < j1; ++j)
      s += __hip_atomic_load(&src[j], __ATOMIC_RELAXED,
                             __HIP_MEMORY_SCOPE_AGENT);
    s += __shfl_xor(s, 1); s += __shfl_xor(s, 2); s += __shfl_xor(s, 4);
    if (c == 0) tot[f] = s;
  }
  __syncthreads();
  if (tid >= 64) return;

  const double EPSD = 1e-8;
  double tv = (tid < ES) ? tot[2 + tid] : 0.0;
  double sv = (tid < ES) ? tot[2 + ES + tid] : 0.0;
  double tsum = tv, ssum = sv;
#pragma unroll
  for (int off = 8; off; off >>= 1) {
    tsum += __shfl_xor(tsum, off);
    ssum += __shfl_xor(ssum, off);
  }
  double ta = tv / tsum + EPSD;
  double sa = sv / ssum + EPSD;
  double ta2 = (tid < ES) ? ta : 0.0;
  double sa2 = (tid < ES) ? sa : 0.0;
#pragma unroll
  for (int off = 8; off; off >>= 1) {
    ta2 += __shfl_xor(ta2, off);
    sa2 += __shfl_xor(sa2, off);
  }
  ta2 += (double)(ET - ES) * EPSD;   // 112 zero bins contribute EPS each
  sa2 += (double)(ET - ES) * EPSD;
  double tn = ta / ta2, sn = sa / sa2;
  double ci = (tid < ES) ? tn * (log(tn) - log(sn)) : 0.0;
#pragma unroll
  for (int off = 8; off; off >>= 1) ci += __shfl_xor(ci, off);

  if (tid == 0) {
    double ta0 = EPSD / ta2, sa0 = EPSD / sa2;
    double cov = ci + (double)(ET - ES) * ta0 * (log(ta0) - log(sa0));
    cov /= (double)ET;
    double feat = tot[1] / fmax(tot[0], EPSD);
    out[0] = (float)(feat + 0.5 * cov);
  }
}

extern "C" void kernel_launch(void* const* d_in, const int* in_sizes, int n_in,
                              void* d_out, int out_size, void* d_ws, size_t ws_size,
                              hipStream_t stream) {
  const float* tg = (const float*)d_in[0];
  const float* sg = (const float*)d_in[1];
  const int*   am = (const int*)d_in[4];
  const int N = in_sizes[4];  // B*S tokens

  // key chain: key = jax.random.key(42); per step foldlike split (partitionable)
  uint32_t key0 = 0u, key1 = 42u;
  uint32_t subs[3][2];
  for (int k = 0; k < 3; ++k) {
    uint32_t a0 = 0u, a1 = 0u; tf2x32(key0, key1, a0, a1);  // new key
    uint32_t b0 = 0u, b1 = 1u; tf2x32(key0, key1, b0, b1);  // subkey
    subs[k][0] = b0; subs[k][1] = b1;
    key0 = a0; key1 = a1;
  }

  double* acc = (double*)d_ws;

  int blocks = (N + 15) / 16;
  if (blocks > 2048) blocks = 2048;
  if (blocks < 1) blocks = 1;
  const int total_waves = blocks * 4;

  sample_kernel<<<blocks, 256, 0, stream>>>(
      tg, sg, am, acc,
      subs[0][0], subs[0][1], subs[1][0], subs[1][1], subs[2][0], subs[2][1],
      N, total_waves);
  finalize_kernel<<<1, 256, 0, stream>>>(acc, blocks, (float*)d_out);
}